// Round 2
// baseline (2977.945 us; speedup 1.0000x reference)
//
#include <hip/hip_runtime.h>
#include <hip/hip_fp16.h>

#define B_   32
#define LQ_  96
#define NK_  2048
#define D_   384
#define H_   8
#define DH_  48
#define FF_  1536
#define MQ_  (B_*LQ_)   // 3072
#define SATT 8          // attention split-K chunks

typedef float  f32x4  __attribute__((ext_vector_type(4)));
typedef __bf16 bf16x8 __attribute__((ext_vector_type(8)));

__device__ __forceinline__ unsigned short f2bf(float f) {
  union { float f; unsigned u; } v; v.f = f;
  unsigned r = v.u + 0x7fffu + ((v.u >> 16) & 1u);
  return (unsigned short)(r >> 16);
}

// async global->LDS DMA, 16B per lane; LDS dest must be wave-uniform base + lane*16
__device__ __forceinline__ void ld_g2l(const unsigned short* g, unsigned short* l) {
  __builtin_amdgcn_global_load_lds(
      (const __attribute__((address_space(1))) void*)g,
      (__attribute__((address_space(3))) void*)l, 16, 0, 0);
}

// ---------------- time embedding ---------------------------------------------
__global__ void time_embed_kernel(const float* __restrict__ ts,
                                  const float* __restrict__ w1, const float* __restrict__ b1,
                                  const float* __restrict__ w2, const float* __restrict__ b2,
                                  float* __restrict__ s_out) {
  int b = blockIdx.x, d = threadIdx.x;
  __shared__ float pe[384];
  __shared__ float h1[384];
  float t = ts[b];
  int dd = (d < 192) ? d : d - 192;
  float f = expf((float)dd * (-9.210340371976184f / 191.0f));
  float ang = t * f;
  pe[d] = (d < 192) ? sinf(ang) : cosf(ang);
  __syncthreads();
  float acc = b1[d];
  for (int k = 0; k < 384; ++k) acc += pe[k] * w1[k * 384 + d];
  h1[d] = fmaxf(acc, 0.f);
  __syncthreads();
  acc = b2[d];
  for (int k = 0; k < 384; ++k) acc += h1[k] * w2[k * 384 + d];
  s_out[b * 384 + d] = acc / (1.f + expf(-acc));   // silu
}

// ---------------- AdaLN modulation ------------------------------------------
__global__ void adaln_mod_kernel(const float* __restrict__ s,
                                 const float* __restrict__ aw, const float* __restrict__ ab,
                                 float* __restrict__ mod) {
  int b = blockIdx.x, l = blockIdx.y, c = threadIdx.x;
  __shared__ float ss[384];
  if (c < 384) ss[c] = s[b * 384 + c];
  __syncthreads();
  float acc = ab[l * 768 + c];
  const float* w = aw + (long)l * 384 * 768;
  for (int k = 0; k < 384; ++k) acc += ss[k] * w[k * 768 + c];
  mod[((long)l * 32 + b) * 768 + c] = acc;
}

// ---------------- RoPE packed half2 table: cs[b][n][p] = (cos, sin) ----------
// combined layout: n in [0,2048) from k_xyz, [2048,2144) from q_xyz; ldn=2144
__global__ void rope_pack_kernel(const float* __restrict__ xyz, __half2* __restrict__ cs,
                                 int total, int N, int ldn, int noff) {
  for (int i = blockIdx.x * blockDim.x + threadIdx.x; i < total;
       i += gridDim.x * blockDim.x) {
    int p = i % 192;
    int n = (i / 192) % N;
    int b = i / (192 * N);
    int a = p >> 6, j = p & 63;
    float div = __expf((float)j * (-9.210340371976184f / 64.0f));
    float ang = xyz[((long)b * N + n) * 3 + a] * div;
    float sv, cv;
    __sincosf(ang, &sv, &cv);
    cs[((long)b * ldn + noff + n) * 192 + p] = __floats2half2_rn(cv, sv);
  }
}

// ---------------- cast f32->bf16 with type_emb add at rows 2046/2047 ---------
__global__ void cast_type_kernel(const float* __restrict__ in, const float* __restrict__ temb,
                                 unsigned short* __restrict__ out, long total, int N) {
  for (long i = blockIdx.x * (long)blockDim.x + threadIdx.x; i < total;
       i += (long)gridDim.x * blockDim.x) {
    int d = (int)(i % 384);
    int n = (int)((i / 384) % N);
    float v = in[i];
    if (n == 2046) v += temb[3 * 384 + d];
    else if (n == 2047) v += temb[4 * 384 + d];
    out[i] = f2bf(v);
  }
}

// ---------------- weight transpose+cast --------------------------------------
__global__ void wtrans_kernel(const float* __restrict__ in, unsigned short* __restrict__ out,
                              long total, int K, int N) {
  for (long i = blockIdx.x * (long)blockDim.x + threadIdx.x; i < total;
       i += (long)gridDim.x * blockDim.x) {
    long l = i / ((long)K * N);
    long rem = i - l * (long)K * N;
    int n = (int)(rem / K);
    int k = (int)(rem % K);
    out[i] = f2bf(in[l * (long)K * N + (long)k * N + n]);
  }
}

// ---------------- AdaLN apply ------------------------------------------------
__global__ void modx_kernel(const float* __restrict__ x, const float* __restrict__ modl,
                            unsigned short* __restrict__ xq) {
  int i = blockIdx.x * blockDim.x + threadIdx.x;
  if (i >= MQ_ * D_) return;
  int d = i % 384;
  int b = (i / 384) / 96;
  float sc = modl[b * 768 + d];
  float sh = modl[b * 768 + 384 + d];
  xq[i] = f2bf(x[i] * (1.f + sc) + sh);
}

// ---------------- MFMA GEMM: C[M,Nt] = A[M,K] x Bt[Nt,K]^T + bias ------------
// 128x128 tile, BK=32, global_load_lds(16B) staging, m97 2-barrier K-loop.
// grid: (x = col tiles, y = row tiles) -> consecutive blocks share A row-tile.
#define EPI_V      0   // bf16, head-major [B,H,N,48]
#define EPI_RELU   1   // bf16 relu, row-major
#define EPI_F32    2   // f32, row-major
#define EPI_ROPE_Q 3   // rope + bf16, row-major
#define EPI_ROPE_K 4   // rope + bf16, head-major

template <int EPI>
__global__ __launch_bounds__(256)
void gemm_bt(const unsigned short* __restrict__ A, const unsigned short* __restrict__ Bt,
             const float* __restrict__ bias, void* __restrict__ Cout,
             int M, int Nt, int K,
             const __half2* __restrict__ cs, int tabOff, int nPerRow) {
  __shared__ __align__(16) unsigned short As[128 * 32];
  __shared__ __align__(16) unsigned short Bs[128 * 32];
  int tid = threadIdx.x, lane = tid & 63;
  int wid = tid >> 6;
  int wm = (wid >> 1) * 64, wn = (wid & 1) * 64;
  int bn = blockIdx.x * 128;
  long bm = (long)blockIdx.y * 128;
  int r0 = tid >> 2, c0 = (tid & 3) * 8;
  const unsigned short* gA0 = A + (bm + r0) * K + c0;
  const unsigned short* gA1 = A + (bm + 64 + r0) * K + c0;
  const unsigned short* gB0 = Bt + (long)(bn + r0) * K + c0;
  const unsigned short* gB1 = Bt + (long)(bn + 64 + r0) * K + c0;
  f32x4 acc[4][4] = {};
  int nk = K >> 5;
  int la = lane & 15, lg = (lane >> 4) * 8;
  for (int kc = 0; kc < nk; ++kc) {
    if (kc) __syncthreads();               // all frag reads of prev tile done
    ld_g2l(gA0, &As[tid * 8]);
    ld_g2l(gA1, &As[2048 + tid * 8]);
    ld_g2l(gB0, &Bs[tid * 8]);
    ld_g2l(gB1, &Bs[2048 + tid * 8]);
    gA0 += 32; gA1 += 32; gB0 += 32; gB1 += 32;
    __syncthreads();                        // drains vmcnt -> LDS populated
    bf16x8 af[4], bfr[4];
#pragma unroll
    for (int i = 0; i < 4; ++i) af[i] = *(const bf16x8*)&As[(wm + i * 16 + la) * 32 + lg];
#pragma unroll
    for (int j = 0; j < 4; ++j) bfr[j] = *(const bf16x8*)&Bs[(wn + j * 16 + la) * 32 + lg];
#pragma unroll
    for (int i = 0; i < 4; ++i)
#pragma unroll
      for (int j = 0; j < 4; ++j)
        acc[i][j] = __builtin_amdgcn_mfma_f32_16x16x32_bf16(af[i], bfr[j], acc[i][j], 0, 0, 0);
  }
  int lr = (lane >> 4) * 4;
#pragma unroll
  for (int i = 0; i < 4; ++i) {
#pragma unroll
    for (int r = 0; r < 4; ++r) {
      int row = (int)bm + wm + i * 16 + lr + r;
      int bb = 0, nn = 0; long ti = 0;
      if (EPI == EPI_ROPE_Q || EPI == EPI_ROPE_K || EPI == EPI_V) {
        bb = row / nPerRow;
        nn = row - bb * nPerRow;
      }
      if (EPI == EPI_ROPE_Q || EPI == EPI_ROPE_K)
        ti = ((long)bb * 2144 + tabOff + nn) * 192;
#pragma unroll
      for (int j = 0; j < 4; ++j) {
        int col = bn + wn + j * 16 + la;
        float v = acc[i][j][r] + bias[col];
        if (EPI == EPI_F32) {
          ((float*)Cout)[(long)row * Nt + col] = v;
        } else if (EPI == EPI_RELU) {
          ((unsigned short*)Cout)[(long)row * Nt + col] = f2bf(fmaxf(v, 0.f));
        } else if (EPI == EPI_V) {
          ((unsigned short*)Cout)[((long)(bb * 8 + col / 48) * nPerRow + nn) * 48 + (col % 48)] = f2bf(v);
        } else {
          float pv = __shfl_xor(v, 1);  // pair partner col^1 lives in lane^1
          int p = ((col >> 7) << 6) + ((col & 127) >> 1);
          __half2 hv = cs[ti + p];
          float cc = __low2float(hv), ssv = __high2float(hv);
          float o = (col & 1) ? (v * cc + pv * ssv) : (v * cc - pv * ssv);
          if (EPI == EPI_ROPE_Q)
            ((unsigned short*)Cout)[(long)row * Nt + col] = f2bf(o);
          else
            ((unsigned short*)Cout)[((long)(bb * 8 + col / 48) * nPerRow + nn) * 48 + (col % 48)] = f2bf(o);
        }
      }
    }
  }
}

// ---------------- split-K flash attention -------------------------------------
// K/V head-major [B*H, N, 48]; grid (H, B, SATT); 6 waves x 16 q-rows.
// Writes unnormalized partial O + (m, l) per (s, b, h, q).
__global__ __launch_bounds__(384)
void attn_part_kernel(const unsigned short* __restrict__ Q, const unsigned short* __restrict__ Kg,
                      const unsigned short* __restrict__ Vg, float* __restrict__ Opart,
                      float* __restrict__ Ml, int N, int S) {
  int h = blockIdx.x, b = blockIdx.y, s = blockIdx.z;
  int tid = threadIdx.x, lane = tid & 63, w = tid >> 6;
  __shared__ __align__(16) unsigned short Qs[96][64];
  __shared__ __align__(16) unsigned short Ks[32][72];  // stride 72: b128 reads ~conflict-free
  __shared__ __align__(16) unsigned short Vs[32][58];  // stride 58: scalar reads conflict-free
  __shared__ __align__(16) unsigned short Ps[6][16][40];
  const uint4 z4 = {0u, 0u, 0u, 0u};
  for (int e = tid; e < 576; e += 384) {
    int row = e / 6, g = e % 6;
    *(uint4*)&Qs[row][g * 8] = *(const uint4*)&Q[((long)b * 96 + row) * 384 + h * 48 + g * 8];
  }
  for (int e = tid; e < 192; e += 384) {
    int row = e >> 1, g = e & 1;
    *(uint4*)&Qs[row][48 + g * 8] = z4;
  }
  if (tid < 96) {                            // Ks pad cols 48..71 = 0 (once)
    int row = tid / 3, g = tid % 3;
    *(uint4*)&Ks[row][48 + g * 8] = z4;
  }
  __syncthreads();
  int la = lane & 15, lg = (lane >> 4) * 8;
  bf16x8 qf0 = *(const bf16x8*)&Qs[w * 16 + la][lg];
  bf16x8 qf1 = *(const bf16x8*)&Qs[w * 16 + la][32 + lg];
  float m[4], lsum[4];
  f32x4 of[3] = {};
#pragma unroll
  for (int r = 0; r < 4; ++r) { m[r] = -1e30f; lsum[r] = 0.f; }
  int ntile = N >> 5;
  int t0 = (s * ntile) / S, t1 = ((s + 1) * ntile) / S;
  int stt = (tid < 192) ? tid : tid - 192;
  int srow = stt / 6, sg = (stt % 6) * 8;
  const unsigned short* gbase = (tid < 192) ? Kg : Vg;
  const uint4* gsrc = (const uint4*)(gbase + ((long)(b * 8 + h) * N + srow) * 48 + sg);
  uint4 pref = gsrc[(long)t0 * 192];   // 32 rows * 48 elem = 192 uint4 per tile
  const float SCALE = 0.14433756729740643f;  // 1/sqrt(48)
  for (int it = t0; it < t1; ++it) {
    if (tid < 192) {
      *(uint4*)&Ks[srow][sg] = pref;
    } else {
      unsigned* dv = (unsigned*)&Vs[srow][sg];   // 4B-aligned (stride 116B)
      dv[0] = pref.x; dv[1] = pref.y; dv[2] = pref.z; dv[3] = pref.w;
    }
    __syncthreads();
    if (it + 1 < t1) pref = gsrc[(long)(it + 1) * 192];
    f32x4 sc[2] = {};
#pragma unroll
    for (int ctile = 0; ctile < 2; ++ctile) {
      bf16x8 kf0 = *(const bf16x8*)&Ks[ctile * 16 + la][lg];
      bf16x8 kf1 = *(const bf16x8*)&Ks[ctile * 16 + la][32 + lg];
      sc[ctile] = __builtin_amdgcn_mfma_f32_16x16x32_bf16(qf0, kf0, sc[ctile], 0, 0, 0);
      sc[ctile] = __builtin_amdgcn_mfma_f32_16x16x32_bf16(qf1, kf1, sc[ctile], 0, 0, 0);
    }
    float mx[4], rs[4], al[4];
#pragma unroll
    for (int r = 0; r < 4; ++r) {
      sc[0][r] *= SCALE; sc[1][r] *= SCALE;
      mx[r] = fmaxf(sc[0][r], sc[1][r]);
    }
#pragma unroll
    for (int d = 1; d < 16; d <<= 1)
#pragma unroll
      for (int r = 0; r < 4; ++r) mx[r] = fmaxf(mx[r], __shfl_xor(mx[r], d));
#pragma unroll
    for (int r = 0; r < 4; ++r) {
      float mn = fmaxf(m[r], mx[r]);
      al[r] = __expf(m[r] - mn);
      sc[0][r] = __expf(sc[0][r] - mn);
      sc[1][r] = __expf(sc[1][r] - mn);
      rs[r] = sc[0][r] + sc[1][r];
      m[r] = mn;
    }
#pragma unroll
    for (int d = 1; d < 16; d <<= 1)
#pragma unroll
      for (int r = 0; r < 4; ++r) rs[r] += __shfl_xor(rs[r], d);
#pragma unroll
    for (int r = 0; r < 4; ++r) lsum[r] = lsum[r] * al[r] + rs[r];
#pragma unroll
    for (int dt = 0; dt < 3; ++dt)
#pragma unroll
      for (int r = 0; r < 4; ++r) of[dt][r] *= al[r];
    int prow = (lane >> 4) * 4;
#pragma unroll
    for (int ctile = 0; ctile < 2; ++ctile)
#pragma unroll
      for (int r = 0; r < 4; ++r)
        Ps[w][prow + r][ctile * 16 + la] = f2bf(sc[ctile][r]);
    __asm__ volatile("s_waitcnt lgkmcnt(0)" ::: "memory");  // wave-local C->A relayout
    bf16x8 pf = *(const bf16x8*)&Ps[w][la][lg];
#pragma unroll
    for (int dt = 0; dt < 3; ++dt) {
      union { bf16x8 v; unsigned short u[8]; } vf;
#pragma unroll
      for (int j = 0; j < 8; ++j) vf.u[j] = Vs[lg + j][dt * 16 + la];
      of[dt] = __builtin_amdgcn_mfma_f32_16x16x32_bf16(pf, vf.v, of[dt], 0, 0, 0);
    }
    __syncthreads();
  }
  long base = (((long)s * 32 + b) * 8 + h) * 96;
#pragma unroll
  for (int r = 0; r < 4; ++r) {
    int qrow = w * 16 + (lane >> 4) * 4 + r;
#pragma unroll
    for (int dt = 0; dt < 3; ++dt)
      Opart[(base + qrow) * 48 + dt * 16 + la] = of[dt][r];
    if (la == 0) {
      Ml[(base + qrow) * 2]     = m[r];
      Ml[(base + qrow) * 2 + 1] = lsum[r];
    }
  }
}

// ---------------- split-K combine --------------------------------------------
__global__ __launch_bounds__(384)
void attn_combine_kernel(const float* __restrict__ Opart, const float* __restrict__ Ml,
                         unsigned short* __restrict__ O, int S) {
  int h = blockIdx.x, b = blockIdx.y;
  for (int e = threadIdx.x; e < 96 * 48; e += 384) {
    int q = e / 48, d = e % 48;
    float M = -1e30f;
    for (int s = 0; s < S; ++s)
      M = fmaxf(M, Ml[(((long)s * 256 + b * 8 + h) * 96 + q) * 2]);
    float L = 0.f, acc = 0.f;
    for (int s = 0; s < S; ++s) {
      long ib = ((long)s * 256 + b * 8 + h) * 96 + q;
      float wgt = __expf(Ml[ib * 2] - M);
      L += Ml[ib * 2 + 1] * wgt;
      acc += Opart[ib * 48 + d] * wgt;
    }
    O[((long)b * 96 + q) * 384 + h * 48 + d] = f2bf(acc / L);
  }
}

// ---------------- residual + LayerNorm ---------------------------------------
__global__ __launch_bounds__(128)
void ln_res_kernel(const float* __restrict__ xin, const float* __restrict__ delta,
                   const float* __restrict__ g, const float* __restrict__ bt,
                   float* __restrict__ xout, unsigned short* __restrict__ xbf) {
  int row = blockIdx.x, tid = threadIdx.x;
  __shared__ float red[128];
  float v[3];
#pragma unroll
  for (int i = 0; i < 3; ++i) {
    int d = tid + i * 128;
    v[i] = xin[(long)row * 384 + d] + delta[(long)row * 384 + d];
  }
  red[tid] = v[0] + v[1] + v[2];
  __syncthreads();
  for (int t = 64; t > 0; t >>= 1) { if (tid < t) red[tid] += red[tid + t]; __syncthreads(); }
  float mean = red[0] / 384.f;
  __syncthreads();
  float q = 0.f;
#pragma unroll
  for (int i = 0; i < 3; ++i) { float d0 = v[i] - mean; q += d0 * d0; }
  red[tid] = q;
  __syncthreads();
  for (int t = 64; t > 0; t >>= 1) { if (tid < t) red[tid] += red[tid + t]; __syncthreads(); }
  float rstd = rsqrtf(red[0] / 384.f + 1e-5f);
#pragma unroll
  for (int i = 0; i < 3; ++i) {
    int d = tid + i * 128;
    float o = (v[i] - mean) * rstd * g[d] + bt[d];
    xout[(long)row * 384 + d] = o;
    xbf[(long)row * 384 + d] = f2bf(o);
  }
}

// ---------------- fp32 row GEMM for the MLP heads ----------------------------
__global__ void rowgemm_kernel(const float* __restrict__ A, const float* __restrict__ W,
                               const float* __restrict__ bias, float* __restrict__ out,
                               int K, int Nc, int ldo, int ooff,
                               int grp, int gstride, int roff, int relu) {
  int r = blockIdx.x, tid = threadIdx.x;
  long arow = (grp > 0) ? ((long)(r / grp) * gstride + roff + (r % grp)) : r;
  __shared__ float as[1536];
  for (int k = tid; k < K; k += blockDim.x) as[k] = A[arow * K + k];
  __syncthreads();
  if (tid < Nc) {
    float acc = bias[tid];
    for (int k = 0; k < K; ++k) acc += as[k] * W[(long)k * Nc + tid];
    if (relu) acc = fmaxf(acc, 0.f);
    out[(long)r * ldo + ooff + tid] = acc;
  }
}

// =============================================================================
extern "C" void kernel_launch(void* const* d_in, const int* in_sizes, int n_in,
                              void* d_out, int out_size, void* d_ws, size_t ws_size,
                              hipStream_t stream) {
  const float* q_in    = (const float*)d_in[0];
  const float* k_cross = (const float*)d_in[1];
  const float* k_self  = (const float*)d_in[2];
  const float* q_xyz   = (const float*)d_in[3];
  const float* k_xyz   = (const float*)d_in[4];
  const float* tsteps  = (const float*)d_in[5];
  const float* t_w1 = (const float*)d_in[6];
  const float* t_b1 = (const float*)d_in[7];
  const float* t_w2 = (const float*)d_in[8];
  const float* t_b2 = (const float*)d_in[9];
  const float* type_emb = (const float*)d_in[10];
  const float* ada_w = (const float*)d_in[11];
  const float* ada_b = (const float*)d_in[12];
  const float* wq = (const float*)d_in[13]; const float* bq = (const float*)d_in[14];
  const float* wk = (const float*)d_in[15]; const float* bk = (const float*)d_in[16];
  const float* wv = (const float*)d_in[17]; const float* bv = (const float*)d_in[18];
  const float* wo = (const float*)d_in[19]; const float* bo = (const float*)d_in[20];
  const float* ln1g = (const float*)d_in[21]; const float* ln1b = (const float*)d_in[22];
  const float* fw1 = (const float*)d_in[23]; const float* fb1 = (const float*)d_in[24];
  const float* fw2 = (const float*)d_in[25]; const float* fb2 = (const float*)d_in[26];
  const float* ln2g = (const float*)d_in[27]; const float* ln2b = (const float*)d_in[28];
  const float* hw[9]; const float* hb[9];
  for (int i = 0; i < 9; ++i) { hw[i] = (const float*)d_in[29 + 2 * i]; hb[i] = (const float*)d_in[30 + 2 * i]; }

  char* ws = (char*)d_ws;
  size_t off = 0;
  auto alloc = [&](size_t bytes) -> void* {
    void* p = ws + off;
    off += (bytes + 255) & ~(size_t)255;
    return p;
  };
  float* s_silu = (float*)alloc((size_t)32 * 384 * 4);
  float* mod    = (float*)alloc((size_t)6 * 32 * 768 * 4);
  __half2* cs_all = (__half2*)alloc((size_t)32 * 2144 * 192 * 4);
  unsigned short* kcb  = (unsigned short*)alloc((size_t)32 * 2048 * 384 * 2);
  unsigned short* ksb  = (unsigned short*)alloc((size_t)32 * 2144 * 384 * 2);
  unsigned short* wqt  = (unsigned short*)alloc((size_t)6 * 384 * 384 * 2);
  unsigned short* wkt  = (unsigned short*)alloc((size_t)6 * 384 * 384 * 2);
  unsigned short* wvt  = (unsigned short*)alloc((size_t)6 * 384 * 384 * 2);
  unsigned short* wot  = (unsigned short*)alloc((size_t)6 * 384 * 384 * 2);
  unsigned short* fw1t = (unsigned short*)alloc((size_t)6 * 384 * 1536 * 2);
  unsigned short* fw2t = (unsigned short*)alloc((size_t)6 * 384 * 1536 * 2);
  float* x            = (float*)alloc((size_t)MQ_ * 384 * 4);
  unsigned short* xbf  = (unsigned short*)alloc((size_t)MQ_ * 384 * 2);
  unsigned short* xqb  = (unsigned short*)alloc((size_t)MQ_ * 384 * 2);
  unsigned short* qrope= (unsigned short*)alloc((size_t)MQ_ * 384 * 2);
  unsigned short* Kc   = (unsigned short*)alloc((size_t)32 * 8 * 2144 * 48 * 2);
  unsigned short* Vc   = (unsigned short*)alloc((size_t)32 * 8 * 2144 * 48 * 2);
  unsigned short* aout = (unsigned short*)alloc((size_t)MQ_ * 384 * 2);
  float* tmp          = (float*)alloc((size_t)MQ_ * 384 * 4);
  unsigned short* ffh  = (unsigned short*)alloc((size_t)MQ_ * 1536 * 2);
  float* h1b          = (float*)alloc((size_t)1024 * 384 * 4);
  float* h2b          = (float*)alloc((size_t)1024 * 384 * 4);
  float* Opart        = (float*)alloc((size_t)SATT * 32 * 8 * 96 * 48 * 4);
  float* Ml           = (float*)alloc((size_t)SATT * 32 * 8 * 96 * 2 * 4);
  (void)ws_size; (void)in_sizes; (void)n_in; (void)out_size;

  // ---- prep (layer-invariant) ----
  time_embed_kernel<<<32, 384, 0, stream>>>(tsteps, t_w1, t_b1, t_w2, t_b2, s_silu);
  adaln_mod_kernel<<<dim3(32, 6), 768, 0, stream>>>(s_silu, ada_w, ada_b, mod);
  rope_pack_kernel<<<4096, 256, 0, stream>>>(k_xyz, cs_all, 32 * 2048 * 192, 2048, 2144, 0);
  rope_pack_kernel<<<1024, 256, 0, stream>>>(q_xyz, cs_all, 32 * 96 * 192, 96, 2144, 2048);
  cast_type_kernel<<<4096, 256, 0, stream>>>(k_cross, type_emb, kcb, (long)32 * 2048 * 384, 2048);
  cast_type_kernel<<<4096, 256, 0, stream>>>(k_self, type_emb, ksb, (long)32 * 2144 * 384, 2144);
  wtrans_kernel<<<1024, 256, 0, stream>>>(wq, wqt, (long)6 * 384 * 384, 384, 384);
  wtrans_kernel<<<1024, 256, 0, stream>>>(wk, wkt, (long)6 * 384 * 384, 384, 384);
  wtrans_kernel<<<1024, 256, 0, stream>>>(wv, wvt, (long)6 * 384 * 384, 384, 384);
  wtrans_kernel<<<1024, 256, 0, stream>>>(wo, wot, (long)6 * 384 * 384, 384, 384);
  wtrans_kernel<<<2048, 256, 0, stream>>>(fw1, fw1t, (long)6 * 384 * 1536, 384, 1536);
  wtrans_kernel<<<2048, 256, 0, stream>>>(fw2, fw2t, (long)6 * 1536 * 384, 1536, 384);
  hipMemcpyAsync(x, q_in, (size_t)MQ_ * 384 * 4, hipMemcpyDeviceToDevice, stream);

  // ---- 6 transformer layers ----
  for (int l = 0; l < 6; ++l) {
    int Nl = (l < 2) ? 2048 : 2144;
    const unsigned short* kvsrc = (l < 2) ? kcb : ksb;
    modx_kernel<<<(MQ_ * 384 + 255) / 256, 256, 0, stream>>>(x, mod + (long)l * 32 * 768, xqb);
    gemm_bt<EPI_ROPE_Q><<<dim3(3, 24), 256, 0, stream>>>(
        xqb, wqt + (long)l * 384 * 384, bq + l * 384, qrope, MQ_, 384, 384,
        cs_all, 2048, 96);
    gemm_bt<EPI_ROPE_K><<<dim3(3, 32 * Nl / 128), 256, 0, stream>>>(
        kvsrc, wkt + (long)l * 384 * 384, bk + l * 384, Kc, 32 * Nl, 384, 384,
        cs_all, 0, Nl);
    gemm_bt<EPI_V><<<dim3(3, 32 * Nl / 128), 256, 0, stream>>>(
        kvsrc, wvt + (long)l * 384 * 384, bv + l * 384, Vc, 32 * Nl, 384, 384,
        nullptr, 0, Nl);
    attn_part_kernel<<<dim3(8, 32, SATT), 384, 0, stream>>>(qrope, Kc, Vc, Opart, Ml, Nl, SATT);
    attn_combine_kernel<<<dim3(8, 32), 384, 0, stream>>>(Opart, Ml, aout, SATT);
    gemm_bt<EPI_F32><<<dim3(3, 24), 256, 0, stream>>>(
        aout, wot + (long)l * 384 * 384, bo + l * 384, tmp, MQ_, 384, 384,
        nullptr, 0, 96);
    ln_res_kernel<<<MQ_, 128, 0, stream>>>(x, tmp, ln1g + l * 384, ln1b + l * 384, x, xbf);
    gemm_bt<EPI_RELU><<<dim3(12, 24), 256, 0, stream>>>(
        xbf, fw1t + (long)l * 1536 * 384, fb1 + l * 1536, ffh, MQ_, 1536, 384,
        nullptr, 0, 96);
    gemm_bt<EPI_F32><<<dim3(3, 24), 256, 0, stream>>>(
        ffh, fw2t + (long)l * 384 * 1536, fb2 + l * 384, tmp, MQ_, 384, 1536,
        nullptr, 0, 96);
    ln_res_kernel<<<MQ_, 128, 0, stream>>>(x, tmp, ln2g + l * 384, ln2b + l * 384, x, xbf);
  }

  // ---- MLP heads (fp32) ----
  const int ooffs[3] = {0, 31, 62};
  const int nouts[3] = {31, 31, 9};
  for (int hd = 0; hd < 3; ++hd) {
    rowgemm_kernel<<<1024, 384, 0, stream>>>(x, hw[hd * 3 + 0], hb[hd * 3 + 0], h1b,
                                             384, 384, 384, 0, 32, 96, hd * 32, 1);
    rowgemm_kernel<<<1024, 384, 0, stream>>>(h1b, hw[hd * 3 + 1], hb[hd * 3 + 1], h2b,
                                             384, 384, 384, 0, 0, 0, 0, 1);
    rowgemm_kernel<<<1024, 64, 0, stream>>>(h2b, hw[hd * 3 + 2], hb[hd * 3 + 2], (float*)d_out,
                                            384, nouts[hd], 71, ooffs[hd], 0, 0, 0, 0);
  }
}

// Round 3
// 2784.994 us; speedup vs baseline: 1.0693x; 1.0693x over previous
//
#include <hip/hip_runtime.h>
#include <hip/hip_fp16.h>

#define B_   32
#define LQ_  96
#define NK_  2048
#define D_   384
#define H_   8
#define DH_  48
#define FF_  1536
#define MQ_  (B_*LQ_)   // 3072
#define SATT 8          // attention split-K chunks

typedef float  f32x4  __attribute__((ext_vector_type(4)));
typedef __bf16 bf16x8 __attribute__((ext_vector_type(8)));

__device__ __forceinline__ unsigned short f2bf(float f) {
  union { float f; unsigned u; } v; v.f = f;
  unsigned r = v.u + 0x7fffu + ((v.u >> 16) & 1u);
  return (unsigned short)(r >> 16);
}

// async global->LDS DMA, 16B per lane; LDS dest = wave-uniform base + lane*16
__device__ __forceinline__ void ld_g2l(const unsigned short* g, unsigned short* l) {
  __builtin_amdgcn_global_load_lds(
      (const __attribute__((address_space(1))) void*)g,
      (__attribute__((address_space(3))) void*)l, 16, 0, 0);
}

// ---------------- time embedding ---------------------------------------------
__global__ void time_embed_kernel(const float* __restrict__ ts,
                                  const float* __restrict__ w1, const float* __restrict__ b1,
                                  const float* __restrict__ w2, const float* __restrict__ b2,
                                  float* __restrict__ s_out) {
  int b = blockIdx.x, d = threadIdx.x;
  __shared__ float pe[384];
  __shared__ float h1[384];
  float t = ts[b];
  int dd = (d < 192) ? d : d - 192;
  float f = expf((float)dd * (-9.210340371976184f / 191.0f));
  float ang = t * f;
  pe[d] = (d < 192) ? sinf(ang) : cosf(ang);
  __syncthreads();
  float acc = b1[d];
  for (int k = 0; k < 384; ++k) acc += pe[k] * w1[k * 384 + d];
  h1[d] = fmaxf(acc, 0.f);
  __syncthreads();
  acc = b2[d];
  for (int k = 0; k < 384; ++k) acc += h1[k] * w2[k * 384 + d];
  s_out[b * 384 + d] = acc / (1.f + expf(-acc));   // silu
}

// ---------------- AdaLN modulation ------------------------------------------
__global__ void adaln_mod_kernel(const float* __restrict__ s,
                                 const float* __restrict__ aw, const float* __restrict__ ab,
                                 float* __restrict__ mod) {
  int b = blockIdx.x, l = blockIdx.y, c = threadIdx.x;
  __shared__ float ss[384];
  if (c < 384) ss[c] = s[b * 384 + c];
  __syncthreads();
  float acc = ab[l * 768 + c];
  const float* w = aw + (long)l * 384 * 768;
  for (int k = 0; k < 384; ++k) acc += ss[k] * w[k * 768 + c];
  mod[((long)l * 32 + b) * 768 + c] = acc;
}

// ---------------- RoPE packed half2 table ------------------------------------
__global__ void rope_pack_kernel(const float* __restrict__ xyz, __half2* __restrict__ cs,
                                 int total, int N, int ldn, int noff) {
  for (int i = blockIdx.x * blockDim.x + threadIdx.x; i < total;
       i += gridDim.x * blockDim.x) {
    int p = i % 192;
    int n = (i / 192) % N;
    int b = i / (192 * N);
    int a = p >> 6, j = p & 63;
    float div = __expf((float)j * (-9.210340371976184f / 64.0f));
    float ang = xyz[((long)b * N + n) * 3 + a] * div;
    float sv, cv;
    __sincosf(ang, &sv, &cv);
    cs[((long)b * ldn + noff + n) * 192 + p] = __floats2half2_rn(cv, sv);
  }
}

// ---------------- cast f32->bf16 with type_emb add at rows 2046/2047 ---------
__global__ void cast_type_kernel(const float* __restrict__ in, const float* __restrict__ temb,
                                 unsigned short* __restrict__ out, long total, int N) {
  for (long i = blockIdx.x * (long)blockDim.x + threadIdx.x; i < total;
       i += (long)gridDim.x * blockDim.x) {
    int d = (int)(i % 384);
    int n = (int)((i / 384) % N);
    float v = in[i];
    if (n == 2046) v += temb[3 * 384 + d];
    else if (n == 2047) v += temb[4 * 384 + d];
    out[i] = f2bf(v);
  }
}

// ---------------- weight transpose+cast: out[(l*LDN+noff+n)*K+k] = in[l][k][n]
__global__ void wtrans_kernel(const float* __restrict__ in, unsigned short* __restrict__ out,
                              long total, int K, int N, int LDN, int noff) {
  for (long i = blockIdx.x * (long)blockDim.x + threadIdx.x; i < total;
       i += (long)gridDim.x * blockDim.x) {
    long l = i / ((long)K * N);
    long rem = i - l * (long)K * N;
    int n = (int)(rem / K);
    int k = (int)(rem % K);
    out[(l * LDN + noff + n) * K + k] = f2bf(in[l * (long)K * N + (long)k * N + n]);
  }
}

// ---------------- AdaLN apply (layer 0 only) ---------------------------------
__global__ void modx_kernel(const float* __restrict__ x, const float* __restrict__ modl,
                            unsigned short* __restrict__ xq) {
  int i = blockIdx.x * blockDim.x + threadIdx.x;
  if (i >= MQ_ * D_) return;
  int d = i % 384;
  int b = (i / 384) / 96;
  float sc = modl[b * 768 + d];
  float sh = modl[b * 768 + 384 + d];
  xq[i] = f2bf(x[i] * (1.f + sc) + sh);
}

// ---------------- MFMA GEMM, double-buffered DMA, swizzled LDS ---------------
#define EPI_RELU   1   // bf16 relu, row-major
#define EPI_F32    2   // f32, row-major
#define EPI_ROPE_Q 3   // rope * 1/sqrt(48), bf16 row-major
#define EPI_KV     4   // cols<384: rope-K head-major [bh][n][48]; cols>=384: V transposed [bh][48][n]

template <int EPI, int TM>
__global__ __launch_bounds__(256)
void gemm_bt(const unsigned short* __restrict__ A, const unsigned short* __restrict__ Bt,
             const float* __restrict__ biasK, const float* __restrict__ biasV,
             void* __restrict__ Cout, void* __restrict__ Cout2,
             int Nt, int K, const __half2* __restrict__ cs, int tabOff, int nPerRow) {
  __shared__ __align__(16) unsigned short As[2][TM * 32];
  __shared__ __align__(16) unsigned short Bs[2][128 * 32];
  int tid = threadIdx.x, lane = tid & 63, wid = tid >> 6;
  int wm = (wid >> 1) * (TM / 2), wn = (wid & 1) * 64;
  int bn = blockIdx.x * 128;
  long bm = (long)blockIdx.y * TM;
  int r0 = tid >> 2;
  int cg = ((tid & 3) + (tid >> 3)) & 3;   // swizzled source col-group for this slot
  int c0 = cg * 8;
  const unsigned short* gA0 = A + (bm + r0) * K + c0;
  const unsigned short* gA1 = A + (bm + 64 + r0) * K + c0;
  const unsigned short* gB0 = Bt + (long)(bn + r0) * K + c0;
  const unsigned short* gB1 = Bt + (long)(bn + 64 + r0) * K + c0;
  f32x4 acc[TM / 32][4] = {};
  int nk = K >> 5;
  int la = lane & 15, lg8 = lane >> 4;
  // stage tile 0 into buf 0
  ld_g2l(gA0, &As[0][tid * 8]);
  if (TM == 128) ld_g2l(gA1, &As[0][2048 + tid * 8]);
  ld_g2l(gB0, &Bs[0][tid * 8]);
  ld_g2l(gB1, &Bs[0][2048 + tid * 8]);
  gA0 += 32; gA1 += 32; gB0 += 32; gB1 += 32;
  // precompute swizzled LDS read offsets (constant across k-loop)
  int offA[TM / 32], offB[4];
#pragma unroll
  for (int i = 0; i < TM / 32; ++i) {
    int row = wm + i * 16 + la;
    offA[i] = row * 32 + ((lg8 - (row >> 1)) & 3) * 8;
  }
#pragma unroll
  for (int j = 0; j < 4; ++j) {
    int row = wn + j * 16 + la;
    offB[j] = row * 32 + ((lg8 - (row >> 1)) & 3) * 8;
  }
  __syncthreads();   // tile 0 resident
  for (int kc = 0; kc < nk; ++kc) {
    int cur = kc & 1;
    if (kc + 1 < nk) {   // prefetch next tile into other buffer (overlaps compute)
      int nxt = cur ^ 1;
      ld_g2l(gA0, &As[nxt][tid * 8]);
      if (TM == 128) ld_g2l(gA1, &As[nxt][2048 + tid * 8]);
      ld_g2l(gB0, &Bs[nxt][tid * 8]);
      ld_g2l(gB1, &Bs[nxt][2048 + tid * 8]);
      gA0 += 32; gA1 += 32; gB0 += 32; gB1 += 32;
    }
    bf16x8 af[TM / 32], bfr[4];
#pragma unroll
    for (int i = 0; i < TM / 32; ++i) af[i] = *(const bf16x8*)&As[cur][offA[i]];
#pragma unroll
    for (int j = 0; j < 4; ++j) bfr[j] = *(const bf16x8*)&Bs[cur][offB[j]];
#pragma unroll
    for (int i = 0; i < TM / 32; ++i)
#pragma unroll
      for (int j = 0; j < 4; ++j)
        acc[i][j] = __builtin_amdgcn_mfma_f32_16x16x32_bf16(af[i], bfr[j], acc[i][j], 0, 0, 0);
    __syncthreads();   // drains prefetch DMA + all ds_reads of cur
  }
  int lr = lg8 * 4;
  const float SCALE = 0.14433756729740643f;  // 1/sqrt(48)
  bool isV = false;
  const float* bptr = biasK;
  if (EPI == EPI_KV) { isV = (bn >= 384); if (isV) bptr = biasV - 384; }
#pragma unroll
  for (int i = 0; i < TM / 32; ++i) {
#pragma unroll
    for (int r = 0; r < 4; ++r) {
      int row = (int)bm + wm + i * 16 + lr + r;
      int bb = 0, nn = 0; long ti = 0;
      if (EPI == EPI_ROPE_Q || EPI == EPI_KV) {
        bb = row / nPerRow;
        nn = row - bb * nPerRow;
        ti = ((long)bb * 2144 + tabOff + nn) * 192;
      }
#pragma unroll
      for (int j = 0; j < 4; ++j) {
        int col = bn + wn + j * 16 + la;
        float v = acc[i][j][r] + bptr[col];
        if (EPI == EPI_F32) {
          ((float*)Cout)[(long)row * Nt + col] = v;
        } else if (EPI == EPI_RELU) {
          ((unsigned short*)Cout)[(long)row * Nt + col] = f2bf(fmaxf(v, 0.f));
        } else if (EPI == EPI_KV && isV) {
          int c = col - 384;
          int h = c / 48, d = c - h * 48;
          ((unsigned short*)Cout2)[((long)((bb << 3) + h) * 48 + d) * nPerRow + nn] = f2bf(v);
        } else {  // RoPE (Q or K)
          float pv = __shfl_xor(v, 1);  // pair partner col^1 lives in lane^1
          int p = ((col >> 7) << 6) + ((col & 127) >> 1);
          __half2 hv = cs[ti + p];
          float cc = __low2float(hv), ssv = __high2float(hv);
          float o = (col & 1) ? (v * cc + pv * ssv) : (v * cc - pv * ssv);
          if (EPI == EPI_ROPE_Q) {
            ((unsigned short*)Cout)[(long)row * Nt + col] = f2bf(o * SCALE);
          } else {
            int h = col / 48, d = col - h * 48;
            ((unsigned short*)Cout)[((long)((bb << 3) + h) * nPerRow + nn) * 48 + d] = f2bf(o);
          }
        }
      }
    }
  }
}

// ---------------- split-K flash attention, fixed-max softmax ------------------
// Q pre-scaled by 1/sqrt(48). K head-major [bh][N][48]; V transposed [bh][48][N].
// lsum via ones-row appended to V (4th PV MFMA). grid (H, B, SATT), 6 waves.
__global__ __launch_bounds__(384)
void attn_part_kernel(const unsigned short* __restrict__ Q, const unsigned short* __restrict__ Kg,
                      const unsigned short* __restrict__ Vtg, float* __restrict__ Opart,
                      float* __restrict__ Lpart, int N, int S) {
  int h = blockIdx.x, b = blockIdx.y, s = blockIdx.z;
  int bh = b * 8 + h;
  int tid = threadIdx.x, lane = tid & 63, w = tid >> 6;
  __shared__ __align__(16) unsigned short Qs[96][64];
  __shared__ __align__(16) unsigned short Ks[32][72];
  __shared__ __align__(16) unsigned short Vst[64][40];   // [d][k]; row48=ones, 49..63=0
  __shared__ __align__(16) unsigned short Ps[6][16][40];
  const uint4 z4 = {0u, 0u, 0u, 0u};
  for (int e = tid; e < 576; e += 384) {
    int row = e / 6, g = e % 6;
    *(uint4*)&Qs[row][g * 8] = *(const uint4*)&Q[((long)b * 96 + row) * 384 + h * 48 + g * 8];
  }
  for (int e = tid; e < 192; e += 384) {
    int row = e >> 1, g = e & 1;
    *(uint4*)&Qs[row][48 + g * 8] = z4;
  }
  if (tid < 96) {                           // Ks pad cols 48..71 = 0 (set once)
    int row = tid / 3, g = tid % 3;
    *(uint4*)&Ks[row][48 + g * 8] = z4;
  }
  // Vst rows 49..63 zero (15 rows x 40 shorts = 75 x uint4)
  if (tid < 75) *(uint4*)&Vst[49][0 + tid * 8] = z4;
  // Vst row 48: cols 0..31 = bf16(1.0), cols 32..39 = 0
  if (tid < 40) Vst[48][tid] = (tid < 32) ? (unsigned short)0x3F80 : (unsigned short)0;
  __syncthreads();
  int la = lane & 15, lg = (lane >> 4) * 8;
  bf16x8 qf0 = *(const bf16x8*)&Qs[w * 16 + la][lg];
  bf16x8 qf1 = *(const bf16x8*)&Qs[w * 16 + la][32 + lg];
  f32x4 of[4] = {};   // [0..2] = O accum, [3] = lsum (col 0)
  int ntile = N >> 5;
  int t0 = (s * ntile) / S, t1 = ((s + 1) * ntile) / S;
  // staging: tid<192 -> K (32 rows x 6 groups); tid>=192 -> V (48 d-rows x 4 groups)
  int stt = (tid < 192) ? tid : tid - 192;
  int krow = stt / 6, ksg = (stt % 6) * 8;
  int vd = stt >> 2, vg = stt & 3;
  const uint4* gK = (const uint4*)(Kg + ((long)bh * N + krow) * 48 + ksg);
  const uint4* gV = (const uint4*)(Vtg + ((long)bh * 48 + vd) * N + vg * 8);
  uint4 pref = (tid < 192) ? gK[(long)t0 * 192] : gV[(long)t0 * 4];
  for (int it = t0; it < t1; ++it) {
    if (tid < 192) *(uint4*)&Ks[krow][ksg] = pref;
    else           *(uint4*)&Vst[vd][vg * 8] = pref;
    __syncthreads();
    if (it + 1 < t1) pref = (tid < 192) ? gK[(long)(it + 1) * 192] : gV[(long)(it + 1) * 4];
    f32x4 sc[2] = {};
#pragma unroll
    for (int ctile = 0; ctile < 2; ++ctile) {
      bf16x8 kf0 = *(const bf16x8*)&Ks[ctile * 16 + la][lg];
      bf16x8 kf1 = *(const bf16x8*)&Ks[ctile * 16 + la][32 + lg];
      sc[ctile] = __builtin_amdgcn_mfma_f32_16x16x32_bf16(qf0, kf0, sc[ctile], 0, 0, 0);
      sc[ctile] = __builtin_amdgcn_mfma_f32_16x16x32_bf16(qf1, kf1, sc[ctile], 0, 0, 0);
    }
    // fixed-max softmax: P = exp(s)  (Q pre-scaled; |s| is O(1), no overflow risk)
    int prow = (lane >> 4) * 4;
#pragma unroll
    for (int ctile = 0; ctile < 2; ++ctile)
#pragma unroll
      for (int r = 0; r < 4; ++r)
        Ps[w][prow + r][ctile * 16 + la] = f2bf(__expf(sc[ctile][r]));
    __asm__ volatile("s_waitcnt lgkmcnt(0)" ::: "memory");  // wave-local C->A relayout
    bf16x8 pf = *(const bf16x8*)&Ps[w][la][lg];
#pragma unroll
    for (int dt = 0; dt < 4; ++dt) {
      bf16x8 vf = *(const bf16x8*)&Vst[dt * 16 + la][lg];
      of[dt] = __builtin_amdgcn_mfma_f32_16x16x32_bf16(pf, vf, of[dt], 0, 0, 0);
    }
    __syncthreads();
  }
  long base = (((long)s * 256 + bh)) * 96;
#pragma unroll
  for (int r = 0; r < 4; ++r) {
    int qrow = w * 16 + (lane >> 4) * 4 + r;
    float L = __shfl(of[3][r], lane & 48);   // broadcast col-0 lane of this quad
#pragma unroll
    for (int dt = 0; dt < 3; ++dt)
      Opart[(base + qrow) * 48 + dt * 16 + la] = of[dt][r];
    if (la == 0) Lpart[base + qrow] = L;
  }
}

// ---------------- split-K combine: O = (sum Opart) / (sum L) ------------------
__global__ __launch_bounds__(384)
void attn_combine_kernel(const float* __restrict__ Opart, const float* __restrict__ Lpart,
                         unsigned short* __restrict__ O, int S) {
  int h = blockIdx.x, b = blockIdx.y;
  int bh = b * 8 + h;
  for (int e = threadIdx.x; e < 96 * 48; e += 384) {
    int q = e / 48, d = e % 48;
    float L = 0.f, acc = 0.f;
    for (int s = 0; s < S; ++s) {
      long ib = ((long)s * 256 + bh) * 96 + q;
      L += Lpart[ib];
      acc += Opart[ib * 48 + d];
    }
    O[((long)b * 96 + q) * 384 + h * 48 + d] = f2bf(acc / L);
  }
}

// ---------------- residual + LayerNorm (+ optional fused AdaLN for next layer)
__global__ __launch_bounds__(128)
void ln_res_kernel(const float* __restrict__ xin, const float* __restrict__ delta,
                   const float* __restrict__ g, const float* __restrict__ bt,
                   const float* __restrict__ modl,
                   float* __restrict__ xout, unsigned short* __restrict__ xbf,
                   unsigned short* __restrict__ xqb) {
  int row = blockIdx.x, tid = threadIdx.x;
  __shared__ float red[128];
  float v[3];
#pragma unroll
  for (int i = 0; i < 3; ++i) {
    int d = tid + i * 128;
    v[i] = xin[(long)row * 384 + d] + delta[(long)row * 384 + d];
  }
  red[tid] = v[0] + v[1] + v[2];
  __syncthreads();
  for (int t = 64; t > 0; t >>= 1) { if (tid < t) red[tid] += red[tid + t]; __syncthreads(); }
  float mean = red[0] / 384.f;
  __syncthreads();
  float q = 0.f;
#pragma unroll
  for (int i = 0; i < 3; ++i) { float d0 = v[i] - mean; q += d0 * d0; }
  red[tid] = q;
  __syncthreads();
  for (int t = 64; t > 0; t >>= 1) { if (tid < t) red[tid] += red[tid + t]; __syncthreads(); }
  float rstd = rsqrtf(red[0] / 384.f + 1e-5f);
  int bb = row / 96;
#pragma unroll
  for (int i = 0; i < 3; ++i) {
    int d = tid + i * 128;
    float o = (v[i] - mean) * rstd * g[d] + bt[d];
    xout[(long)row * 384 + d] = o;
    xbf[(long)row * 384 + d] = f2bf(o);
    if (modl) {
      float sc = modl[bb * 768 + d];
      float sh = modl[bb * 768 + 384 + d];
      xqb[(long)row * 384 + d] = f2bf(o * (1.f + sc) + sh);
    }
  }
}

// ---------------- fp32 row GEMM for the MLP heads ----------------------------
__global__ void rowgemm_kernel(const float* __restrict__ A, const float* __restrict__ W,
                               const float* __restrict__ bias, float* __restrict__ out,
                               int K, int Nc, int ldo, int ooff,
                               int grp, int gstride, int roff, int relu) {
  int r = blockIdx.x, tid = threadIdx.x;
  long arow = (grp > 0) ? ((long)(r / grp) * gstride + roff + (r % grp)) : r;
  __shared__ float as[1536];
  for (int k = tid; k < K; k += blockDim.x) as[k] = A[arow * K + k];
  __syncthreads();
  if (tid < Nc) {
    float acc = bias[tid];
    for (int k = 0; k < K; ++k) acc += as[k] * W[(long)k * Nc + tid];
    if (relu) acc = fmaxf(acc, 0.f);
    out[(long)r * ldo + ooff + tid] = acc;
  }
}

// =============================================================================
extern "C" void kernel_launch(void* const* d_in, const int* in_sizes, int n_in,
                              void* d_out, int out_size, void* d_ws, size_t ws_size,
                              hipStream_t stream) {
  const float* q_in    = (const float*)d_in[0];
  const float* k_cross = (const float*)d_in[1];
  const float* k_self  = (const float*)d_in[2];
  const float* q_xyz   = (const float*)d_in[3];
  const float* k_xyz   = (const float*)d_in[4];
  const float* tsteps  = (const float*)d_in[5];
  const float* t_w1 = (const float*)d_in[6];
  const float* t_b1 = (const float*)d_in[7];
  const float* t_w2 = (const float*)d_in[8];
  const float* t_b2 = (const float*)d_in[9];
  const float* type_emb = (const float*)d_in[10];
  const float* ada_w = (const float*)d_in[11];
  const float* ada_b = (const float*)d_in[12];
  const float* wq = (const float*)d_in[13]; const float* bq = (const float*)d_in[14];
  const float* wk = (const float*)d_in[15]; const float* bk = (const float*)d_in[16];
  const float* wv = (const float*)d_in[17]; const float* bv = (const float*)d_in[18];
  const float* wo = (const float*)d_in[19]; const float* bo = (const float*)d_in[20];
  const float* ln1g = (const float*)d_in[21]; const float* ln1b = (const float*)d_in[22];
  const float* fw1 = (const float*)d_in[23]; const float* fb1 = (const float*)d_in[24];
  const float* fw2 = (const float*)d_in[25]; const float* fb2 = (const float*)d_in[26];
  const float* ln2g = (const float*)d_in[27]; const float* ln2b = (const float*)d_in[28];
  const float* hw[9]; const float* hb[9];
  for (int i = 0; i < 9; ++i) { hw[i] = (const float*)d_in[29 + 2 * i]; hb[i] = (const float*)d_in[30 + 2 * i]; }

  char* ws = (char*)d_ws;
  size_t off = 0;
  auto alloc = [&](size_t bytes) -> void* {
    void* p = ws + off;
    off += (bytes + 255) & ~(size_t)255;
    return p;
  };
  float* s_silu = (float*)alloc((size_t)32 * 384 * 4);
  float* mod    = (float*)alloc((size_t)6 * 32 * 768 * 4);
  __half2* cs_all = (__half2*)alloc((size_t)32 * 2144 * 192 * 4);
  unsigned short* kcb  = (unsigned short*)alloc((size_t)32 * 2048 * 384 * 2);
  unsigned short* ksb  = (unsigned short*)alloc((size_t)32 * 2144 * 384 * 2);
  unsigned short* wqt  = (unsigned short*)alloc((size_t)6 * 384 * 384 * 2);
  unsigned short* wkvt = (unsigned short*)alloc((size_t)6 * 768 * 384 * 2);
  unsigned short* wot  = (unsigned short*)alloc((size_t)6 * 384 * 384 * 2);
  unsigned short* fw1t = (unsigned short*)alloc((size_t)6 * 384 * 1536 * 2);
  unsigned short* fw2t = (unsigned short*)alloc((size_t)6 * 384 * 1536 * 2);
  float* x            = (float*)alloc((size_t)MQ_ * 384 * 4);
  unsigned short* xbf  = (unsigned short*)alloc((size_t)MQ_ * 384 * 2);
  unsigned short* xqb  = (unsigned short*)alloc((size_t)MQ_ * 384 * 2);
  unsigned short* qrope= (unsigned short*)alloc((size_t)MQ_ * 384 * 2);
  unsigned short* Kc   = (unsigned short*)alloc((size_t)256 * 2144 * 48 * 2);
  unsigned short* Vt   = (unsigned short*)alloc((size_t)256 * 48 * 2144 * 2);
  unsigned short* aout = (unsigned short*)alloc((size_t)MQ_ * 384 * 2);
  float* tmp          = (float*)alloc((size_t)MQ_ * 384 * 4);
  unsigned short* ffh  = (unsigned short*)alloc((size_t)MQ_ * 1536 * 2);
  float* h1b          = (float*)alloc((size_t)1024 * 384 * 4);
  float* h2b          = (float*)alloc((size_t)1024 * 384 * 4);
  float* Opart        = (float*)alloc((size_t)SATT * 256 * 96 * 48 * 4);
  float* Lpart        = (float*)alloc((size_t)SATT * 256 * 96 * 4);
  (void)ws_size; (void)in_sizes; (void)n_in; (void)out_size;

  // ---- prep (layer-invariant) ----
  time_embed_kernel<<<32, 384, 0, stream>>>(tsteps, t_w1, t_b1, t_w2, t_b2, s_silu);
  adaln_mod_kernel<<<dim3(32, 6), 768, 0, stream>>>(s_silu, ada_w, ada_b, mod);
  rope_pack_kernel<<<4096, 256, 0, stream>>>(k_xyz, cs_all, 32 * 2048 * 192, 2048, 2144, 0);
  rope_pack_kernel<<<1024, 256, 0, stream>>>(q_xyz, cs_all, 32 * 96 * 192, 96, 2144, 2048);
  cast_type_kernel<<<4096, 256, 0, stream>>>(k_cross, type_emb, kcb, (long)32 * 2048 * 384, 2048);
  cast_type_kernel<<<4096, 256, 0, stream>>>(k_self, type_emb, ksb, (long)32 * 2144 * 384, 2144);
  wtrans_kernel<<<1024, 256, 0, stream>>>(wq, wqt, (long)6 * 384 * 384, 384, 384, 384, 0);
  wtrans_kernel<<<1024, 256, 0, stream>>>(wk, wkvt, (long)6 * 384 * 384, 384, 384, 768, 0);
  wtrans_kernel<<<1024, 256, 0, stream>>>(wv, wkvt, (long)6 * 384 * 384, 384, 384, 768, 384);
  wtrans_kernel<<<1024, 256, 0, stream>>>(wo, wot, (long)6 * 384 * 384, 384, 384, 384, 0);
  wtrans_kernel<<<2048, 256, 0, stream>>>(fw1, fw1t, (long)6 * 384 * 1536, 384, 1536, 1536, 0);
  wtrans_kernel<<<2048, 256, 0, stream>>>(fw2, fw2t, (long)6 * 1536 * 384, 1536, 384, 384, 0);
  hipMemcpyAsync(x, q_in, (size_t)MQ_ * 384 * 4, hipMemcpyDeviceToDevice, stream);
  modx_kernel<<<(MQ_ * 384 + 255) / 256, 256, 0, stream>>>(x, mod, xqb);

  // ---- 6 transformer layers ----
  for (int l = 0; l < 6; ++l) {
    int Nl = (l < 2) ? 2048 : 2144;
    const unsigned short* kvsrc = (l < 2) ? kcb : ksb;
    gemm_bt<EPI_ROPE_Q, 64><<<dim3(3, 48), 256, 0, stream>>>(
        xqb, wqt + (long)l * 384 * 384, bq + l * 384, nullptr, qrope, nullptr,
        384, 384, cs_all, 2048, 96);
    gemm_bt<EPI_KV, 128><<<dim3(6, 32 * Nl / 128), 256, 0, stream>>>(
        kvsrc, wkvt + (long)l * 768 * 384, bk + l * 384, bv + l * 384, Kc, Vt,
        768, 384, cs_all, 0, Nl);
    attn_part_kernel<<<dim3(8, 32, SATT), 384, 0, stream>>>(qrope, Kc, Vt, Opart, Lpart, Nl, SATT);
    attn_combine_kernel<<<dim3(8, 32), 384, 0, stream>>>(Opart, Lpart, aout, SATT);
    gemm_bt<EPI_F32, 64><<<dim3(3, 48), 256, 0, stream>>>(
        aout, wot + (long)l * 384 * 384, bo + l * 384, nullptr, tmp, nullptr,
        384, 384, nullptr, 0, 96);
    ln_res_kernel<<<MQ_, 128, 0, stream>>>(x, tmp, ln1g + l * 384, ln1b + l * 384,
                                           nullptr, x, xbf, nullptr);
    gemm_bt<EPI_RELU, 128><<<dim3(12, 24), 256, 0, stream>>>(
        xbf, fw1t + (long)l * 1536 * 384, fb1 + l * 1536, nullptr, ffh, nullptr,
        1536, 384, nullptr, 0, 96);
    gemm_bt<EPI_F32, 64><<<dim3(3, 48), 256, 0, stream>>>(
        ffh, fw2t + (long)l * 384 * 1536, fb2 + l * 384, nullptr, tmp, nullptr,
        384, 1536, nullptr, 0, 96);
    ln_res_kernel<<<MQ_, 128, 0, stream>>>(x, tmp, ln2g + l * 384, ln2b + l * 384,
                                           (l < 5) ? (mod + (long)(l + 1) * 32 * 768) : nullptr,
                                           x, xbf, xqb);
  }

  // ---- MLP heads (fp32) ----
  const int ooffs[3] = {0, 31, 62};
  const int nouts[3] = {31, 31, 9};
  for (int hd = 0; hd < 3; ++hd) {
    rowgemm_kernel<<<1024, 384, 0, stream>>>(x, hw[hd * 3 + 0], hb[hd * 3 + 0], h1b,
                                             384, 384, 384, 0, 32, 96, hd * 32, 1);
    rowgemm_kernel<<<1024, 384, 0, stream>>>(h1b, hw[hd * 3 + 1], hb[hd * 3 + 1], h2b,
                                             384, 384, 384, 0, 0, 0, 0, 1);
    rowgemm_kernel<<<1024, 64, 0, stream>>>(h2b, hw[hd * 3 + 2], hb[hd * 3 + 2], (float*)d_out,
                                            384, nouts[hd], 71, ooffs[hd], 0, 0, 0, 0);
  }
}

// Round 4
// 2351.316 us; speedup vs baseline: 1.2665x; 1.1844x over previous
//
#include <hip/hip_runtime.h>
#include <hip/hip_fp16.h>

#define B_   32
#define LQ_  96
#define NK_  2048
#define D_   384
#define H_   8
#define DH_  48
#define FF_  1536
#define MQ_  (B_*LQ_)   // 3072
#define SATT 8          // attention split-K chunks

typedef float  f32x4  __attribute__((ext_vector_type(4)));
typedef __bf16 bf16x8 __attribute__((ext_vector_type(8)));

__device__ __forceinline__ unsigned short f2bf(float f) {
  union { float f; unsigned u; } v; v.f = f;
  unsigned r = v.u + 0x7fffu + ((v.u >> 16) & 1u);
  return (unsigned short)(r >> 16);
}

// async global->LDS DMA, 16B per lane; LDS dest = wave-uniform base + lane*16
__device__ __forceinline__ void ld_g2l(const unsigned short* g, unsigned short* l) {
  __builtin_amdgcn_global_load_lds(
      (const __attribute__((address_space(1))) void*)g,
      (__attribute__((address_space(3))) void*)l, 16, 0, 0);
}

// ---------------- time embedding ---------------------------------------------
__global__ void time_embed_kernel(const float* __restrict__ ts,
                                  const float* __restrict__ w1, const float* __restrict__ b1,
                                  const float* __restrict__ w2, const float* __restrict__ b2,
                                  float* __restrict__ s_out) {
  int b = blockIdx.x, d = threadIdx.x;
  __shared__ float pe[384];
  __shared__ float h1[384];
  float t = ts[b];
  int dd = (d < 192) ? d : d - 192;
  float f = expf((float)dd * (-9.210340371976184f / 191.0f));
  float ang = t * f;
  pe[d] = (d < 192) ? sinf(ang) : cosf(ang);
  __syncthreads();
  float acc = b1[d];
  for (int k = 0; k < 384; ++k) acc += pe[k] * w1[k * 384 + d];
  h1[d] = fmaxf(acc, 0.f);
  __syncthreads();
  acc = b2[d];
  for (int k = 0; k < 384; ++k) acc += h1[k] * w2[k * 384 + d];
  s_out[b * 384 + d] = acc / (1.f + expf(-acc));   // silu
}

// ---------------- AdaLN modulation ------------------------------------------
__global__ void adaln_mod_kernel(const float* __restrict__ s,
                                 const float* __restrict__ aw, const float* __restrict__ ab,
                                 float* __restrict__ mod) {
  int b = blockIdx.x, l = blockIdx.y, c = threadIdx.x;
  __shared__ float ss[384];
  if (c < 384) ss[c] = s[b * 384 + c];
  __syncthreads();
  float acc = ab[l * 768 + c];
  const float* w = aw + (long)l * 384 * 768;
  for (int k = 0; k < 384; ++k) acc += ss[k] * w[k * 768 + c];
  mod[((long)l * 32 + b) * 768 + c] = acc;
}

// ---------------- RoPE packed half2 table ------------------------------------
__global__ void rope_pack_kernel(const float* __restrict__ xyz, __half2* __restrict__ cs,
                                 int total, int N, int ldn, int noff) {
  for (int i = blockIdx.x * blockDim.x + threadIdx.x; i < total;
       i += gridDim.x * blockDim.x) {
    int p = i % 192;
    int n = (i / 192) % N;
    int b = i / (192 * N);
    int a = p >> 6, j = p & 63;
    float div = __expf((float)j * (-9.210340371976184f / 64.0f));
    float ang = xyz[((long)b * N + n) * 3 + a] * div;
    float sv, cv;
    __sincosf(ang, &sv, &cv);
    cs[((long)b * ldn + noff + n) * 192 + p] = __floats2half2_rn(cv, sv);
  }
}

// ---------------- cast f32->bf16 with type_emb add at rows 2046/2047 ---------
__global__ void cast_type_kernel(const float* __restrict__ in, const float* __restrict__ temb,
                                 unsigned short* __restrict__ out, long total, int N) {
  for (long i = blockIdx.x * (long)blockDim.x + threadIdx.x; i < total;
       i += (long)gridDim.x * blockDim.x) {
    int d = (int)(i % 384);
    int n = (int)((i / 384) % N);
    float v = in[i];
    if (n == 2046) v += temb[3 * 384 + d];
    else if (n == 2047) v += temb[4 * 384 + d];
    out[i] = f2bf(v);
  }
}

// ---------------- weight transpose+cast: out[(l*LDN+noff+n)*K+k] = in[l][k][n]
__global__ void wtrans_kernel(const float* __restrict__ in, unsigned short* __restrict__ out,
                              long total, int K, int N, int LDN, int noff) {
  for (long i = blockIdx.x * (long)blockDim.x + threadIdx.x; i < total;
       i += (long)gridDim.x * blockDim.x) {
    long l = i / ((long)K * N);
    long rem = i - l * (long)K * N;
    int n = (int)(rem / K);
    int k = (int)(rem % K);
    out[(l * LDN + noff + n) * K + k] = f2bf(in[l * (long)K * N + (long)k * N + n]);
  }
}

// ---------------- AdaLN apply (layer 0 only) ---------------------------------
__global__ void modx_kernel(const float* __restrict__ x, const float* __restrict__ modl,
                            unsigned short* __restrict__ xq) {
  int i = blockIdx.x * blockDim.x + threadIdx.x;
  if (i >= MQ_ * D_) return;
  int d = i % 384;
  int b = (i / 384) / 96;
  float sc = modl[b * 768 + d];
  float sh = modl[b * 768 + 384 + d];
  xq[i] = f2bf(x[i] * (1.f + sc) + sh);
}

// ---------------- MFMA GEMM, double-buffered DMA, swizzled LDS ---------------
#define EPI_RELU   1   // bf16 relu, row-major
#define EPI_F32    2   // f32, row-major
#define EPI_ROPE_Q 3   // rope * 1/sqrt(48), bf16 row-major
#define EPI_KV     4   // cols<384: rope-K head-major [bh][n][48]; cols>=384: V row-major [b][n][384]

// XT>0: 1-D grid, XCD-aware swizzle with XT col-tiles (row-tiles must be %8==0)
// PERM: A row gather for MLP heads: arow = (row>>5)*96 + tabOff + (row&31)
template <int EPI, int TM, int XT, int PERM>
__global__ __launch_bounds__(256)
void gemm_bt(const unsigned short* __restrict__ A, const unsigned short* __restrict__ Bt,
             const float* __restrict__ biasK, const float* __restrict__ biasV,
             void* __restrict__ Cout, void* __restrict__ Cout2,
             int Nt, int K, const __half2* __restrict__ cs, int tabOff, int nPerRow) {
  __shared__ __align__(16) unsigned short As[2][TM * 32];
  __shared__ __align__(16) unsigned short Bs[2][128 * 32];
  int tid = threadIdx.x, lane = tid & 63, wid = tid >> 6;
  int wm = (wid >> 1) * (TM / 2), wn = (wid & 1) * 64;
  int bx, byi;
  if (XT > 0) {
    int id = blockIdx.x;
    int xcd = id & 7, slot = id >> 3;
    bx = slot % XT;
    byi = (slot / XT) * 8 + xcd;   // same row-tile's col-tiles -> same XCD
  } else {
    bx = blockIdx.x; byi = blockIdx.y;
  }
  int bn = bx * 128;
  long bm = (long)byi * TM;
  int r0 = tid >> 2;
  int cg = ((tid & 3) + (tid >> 3)) & 3;   // swizzled source col-group for this slot
  int c0 = cg * 8;
  long ar0 = bm + r0, ar1 = bm + 64 + r0;
  if (PERM) {
    ar0 = (ar0 >> 5) * 96 + tabOff + (ar0 & 31);
    ar1 = (ar1 >> 5) * 96 + tabOff + (ar1 & 31);
  }
  const unsigned short* gA0 = A + ar0 * K + c0;
  const unsigned short* gA1 = A + ar1 * K + c0;
  const unsigned short* gB0 = Bt + (long)(bn + r0) * K + c0;
  const unsigned short* gB1 = Bt + (long)(bn + 64 + r0) * K + c0;
  f32x4 acc[TM / 32][4] = {};
  int nk = K >> 5;
  int la = lane & 15, lg8 = lane >> 4;
  // stage tile 0 into buf 0
  ld_g2l(gA0, &As[0][tid * 8]);
  if (TM == 128) ld_g2l(gA1, &As[0][2048 + tid * 8]);
  ld_g2l(gB0, &Bs[0][tid * 8]);
  ld_g2l(gB1, &Bs[0][2048 + tid * 8]);
  gA0 += 32; gA1 += 32; gB0 += 32; gB1 += 32;
  // precompute swizzled LDS read offsets (constant across k-loop)
  int offA[TM / 32], offB[4];
#pragma unroll
  for (int i = 0; i < TM / 32; ++i) {
    int row = wm + i * 16 + la;
    offA[i] = row * 32 + ((lg8 - (row >> 1)) & 3) * 8;
  }
#pragma unroll
  for (int j = 0; j < 4; ++j) {
    int row = wn + j * 16 + la;
    offB[j] = row * 32 + ((lg8 - (row >> 1)) & 3) * 8;
  }
  __syncthreads();   // tile 0 resident
  for (int kc = 0; kc < nk; ++kc) {
    int cur = kc & 1;
    if (kc + 1 < nk) {   // prefetch next tile into other buffer
      int nxt = cur ^ 1;
      ld_g2l(gA0, &As[nxt][tid * 8]);
      if (TM == 128) ld_g2l(gA1, &As[nxt][2048 + tid * 8]);
      ld_g2l(gB0, &Bs[nxt][tid * 8]);
      ld_g2l(gB1, &Bs[nxt][2048 + tid * 8]);
      gA0 += 32; gA1 += 32; gB0 += 32; gB1 += 32;
    }
    bf16x8 af[TM / 32], bfr[4];
#pragma unroll
    for (int i = 0; i < TM / 32; ++i) af[i] = *(const bf16x8*)&As[cur][offA[i]];
#pragma unroll
    for (int j = 0; j < 4; ++j) bfr[j] = *(const bf16x8*)&Bs[cur][offB[j]];
#pragma unroll
    for (int i = 0; i < TM / 32; ++i)
#pragma unroll
      for (int j = 0; j < 4; ++j)
        acc[i][j] = __builtin_amdgcn_mfma_f32_16x16x32_bf16(af[i], bfr[j], acc[i][j], 0, 0, 0);
    __syncthreads();
  }
  int lr = lg8 * 4;
  const float SCALE = 0.14433756729740643f;  // 1/sqrt(48)
  bool isV = false;
  const float* bptr = biasK;
  if (EPI == EPI_KV) { isV = (bn >= 384); if (isV) bptr = biasV - 384; }
#pragma unroll
  for (int i = 0; i < TM / 32; ++i) {
#pragma unroll
    for (int r = 0; r < 4; ++r) {
      int row = (int)bm + wm + i * 16 + lr + r;
      int bb = 0, nn = 0; long ti = 0;
      if (EPI == EPI_ROPE_Q || EPI == EPI_KV) {
        bb = row / nPerRow;
        nn = row - bb * nPerRow;
        ti = ((long)bb * 2144 + tabOff + nn) * 192;
      }
#pragma unroll
      for (int j = 0; j < 4; ++j) {
        int col = bn + wn + j * 16 + la;
        float v = acc[i][j][r] + bptr[col];
        if (EPI == EPI_F32) {
          ((float*)Cout)[(long)row * Nt + col] = v;
        } else if (EPI == EPI_RELU) {
          ((unsigned short*)Cout)[(long)row * Nt + col] = f2bf(fmaxf(v, 0.f));
        } else if (EPI == EPI_KV && isV) {
          // V: plain row-major [b*N + n][384] -- coalesced 32B runs
          ((unsigned short*)Cout2)[(long)row * 384 + (col - 384)] = f2bf(v);
        } else {  // RoPE (Q or K)
          float pv = __shfl_xor(v, 1);  // pair partner col^1 lives in lane^1
          int p = ((col >> 7) << 6) + ((col & 127) >> 1);
          __half2 hv = cs[ti + p];
          float cc = __low2float(hv), ssv = __high2float(hv);
          float o = (col & 1) ? (v * cc + pv * ssv) : (v * cc - pv * ssv);
          if (EPI == EPI_ROPE_Q) {
            ((unsigned short*)Cout)[(long)row * Nt + col] = f2bf(o * SCALE);
          } else {
            int h = col / 48, d = col - h * 48;
            ((unsigned short*)Cout)[((long)((bb << 3) + h) * nPerRow + nn) * 48 + d] = f2bf(o);
          }
        }
      }
    }
  }
}

// ---------------- split-K flash attention, fixed-max softmax ------------------
// Q pre-scaled by 1/sqrt(48). K head-major [bh][N][48]; V row-major [b][N][384]
// (transposed into LDS by the stager). lsum via ones-row appended to V.
__global__ __launch_bounds__(384)
void attn_part_kernel(const unsigned short* __restrict__ Q, const unsigned short* __restrict__ Kg,
                      const unsigned short* __restrict__ Vrm, float* __restrict__ Opart,
                      float* __restrict__ Lpart, int N, int S) {
  int h = blockIdx.x, b = blockIdx.y, s = blockIdx.z;
  int bh = b * 8 + h;
  int tid = threadIdx.x, lane = tid & 63, w = tid >> 6;
  __shared__ __align__(16) unsigned short Qs[96][64];
  __shared__ __align__(16) unsigned short Ks[32][72];
  __shared__ __align__(16) unsigned short Vst[64][40];   // [d][k]; row48=ones, 49..63=0
  __shared__ __align__(16) unsigned short Ps[6][16][40];
  const uint4 z4 = {0u, 0u, 0u, 0u};
  for (int e = tid; e < 576; e += 384) {
    int row = e / 6, g = e % 6;
    *(uint4*)&Qs[row][g * 8] = *(const uint4*)&Q[((long)b * 96 + row) * 384 + h * 48 + g * 8];
  }
  for (int e = tid; e < 192; e += 384) {
    int row = e >> 1, g = e & 1;
    *(uint4*)&Qs[row][48 + g * 8] = z4;
  }
  if (tid < 96) {                           // Ks pad cols 48..71 = 0 (set once)
    int row = tid / 3, g = tid % 3;
    *(uint4*)&Ks[row][48 + g * 8] = z4;
  }
  // Vst rows 49..63 zero
  if (tid < 75) *(uint4*)&Vst[49][0 + tid * 8] = z4;
  // Vst row 48: cols 0..31 = bf16(1.0), cols 32..39 = 0
  if (tid < 40) Vst[48][tid] = (tid < 32) ? (unsigned short)0x3F80 : (unsigned short)0;
  __syncthreads();
  int la = lane & 15, lg = (lane >> 4) * 8;
  bf16x8 qf0 = *(const bf16x8*)&Qs[w * 16 + la][lg];
  bf16x8 qf1 = *(const bf16x8*)&Qs[w * 16 + la][32 + lg];
  f32x4 of[4] = {};   // [0..2] = O accum, [3] = lsum (col 48 = ones)
  int ntile = N >> 5;
  int t0 = (s * ntile) / S, t1 = ((s + 1) * ntile) / S;
  // staging: tid<192 -> K rows; tid>=192 -> V rows (transpose into LDS)
  int stt = (tid < 192) ? tid : tid - 192;
  int krow = stt / 6, kg = stt % 6;
  const uint4* gsrc = (tid < 192)
      ? (const uint4*)(Kg + ((long)bh * N + krow) * 48 + kg * 8)
      : (const uint4*)(Vrm + ((long)b * N + krow) * 384 + h * 48 + kg * 8);
  int tstep = (tid < 192) ? 192 : 1536;    // uint4 per 32-row tile
  uint4 pref = gsrc[(long)t0 * tstep];
  for (int it = t0; it < t1; ++it) {
    if (tid < 192) {
      *(uint4*)&Ks[krow][kg * 8] = pref;
    } else {
      union { uint4 q; unsigned short u[8]; } t; t.q = pref;
#pragma unroll
      for (int e = 0; e < 8; ++e) Vst[kg * 8 + e][krow] = t.u[e];  // transpose in LDS
    }
    __syncthreads();
    if (it + 1 < t1) pref = gsrc[(long)(it + 1) * tstep];
    f32x4 sc[2] = {};
#pragma unroll
    for (int ctile = 0; ctile < 2; ++ctile) {
      bf16x8 kf0 = *(const bf16x8*)&Ks[ctile * 16 + la][lg];
      bf16x8 kf1 = *(const bf16x8*)&Ks[ctile * 16 + la][32 + lg];
      sc[ctile] = __builtin_amdgcn_mfma_f32_16x16x32_bf16(qf0, kf0, sc[ctile], 0, 0, 0);
      sc[ctile] = __builtin_amdgcn_mfma_f32_16x16x32_bf16(qf1, kf1, sc[ctile], 0, 0, 0);
    }
    // fixed-max softmax: P = exp(s)  (Q pre-scaled; scores O(1), no overflow)
    int prow = (lane >> 4) * 4;
#pragma unroll
    for (int ctile = 0; ctile < 2; ++ctile)
#pragma unroll
      for (int r = 0; r < 4; ++r)
        Ps[w][prow + r][ctile * 16 + la] = f2bf(__expf(sc[ctile][r]));
    __asm__ volatile("s_waitcnt lgkmcnt(0)" ::: "memory");  // wave-local C->A relayout
    bf16x8 pf = *(const bf16x8*)&Ps[w][la][lg];
#pragma unroll
    for (int dt = 0; dt < 4; ++dt) {
      bf16x8 vf = *(const bf16x8*)&Vst[dt * 16 + la][lg];
      of[dt] = __builtin_amdgcn_mfma_f32_16x16x32_bf16(pf, vf, of[dt], 0, 0, 0);
    }
    __syncthreads();
  }
  long base = ((long)s * 256 + bh) * 96;
#pragma unroll
  for (int r = 0; r < 4; ++r) {
    int qrow = w * 16 + (lane >> 4) * 4 + r;
    float L = __shfl(of[3][r], lane & 48);   // col-48 value lives at la==0 of quad
#pragma unroll
    for (int dt = 0; dt < 3; ++dt)
      Opart[(base + qrow) * 48 + dt * 16 + la] = of[dt][r];
    if (la == 0) Lpart[base + qrow] = L;
  }
}

// ---------------- split-K combine: O = (sum Opart) / (sum L) ------------------
__global__ __launch_bounds__(384)
void attn_combine_kernel(const float* __restrict__ Opart, const float* __restrict__ Lpart,
                         unsigned short* __restrict__ O, int S) {
  int h = blockIdx.x, b = blockIdx.y;
  int bh = b * 8 + h;
  for (int e = threadIdx.x; e < 96 * 48; e += 384) {
    int q = e / 48, d = e % 48;
    float L = 0.f, acc = 0.f;
    for (int s = 0; s < S; ++s) {
      long ib = ((long)s * 256 + bh) * 96 + q;
      L += Lpart[ib];
      acc += Opart[ib * 48 + d];
    }
    O[((long)b * 96 + q) * 384 + h * 48 + d] = f2bf(acc / L);
  }
}

// ---------------- residual + LayerNorm (+ optional fused AdaLN for next layer)
__global__ __launch_bounds__(128)
void ln_res_kernel(const float* __restrict__ xin, const float* __restrict__ delta,
                   const float* __restrict__ g, const float* __restrict__ bt,
                   const float* __restrict__ modl,
                   float* __restrict__ xout, unsigned short* __restrict__ xbf,
                   unsigned short* __restrict__ xqb) {
  int row = blockIdx.x, tid = threadIdx.x;
  __shared__ float red[128];
  float v[3];
#pragma unroll
  for (int i = 0; i < 3; ++i) {
    int d = tid + i * 128;
    v[i] = xin[(long)row * 384 + d] + delta[(long)row * 384 + d];
  }
  red[tid] = v[0] + v[1] + v[2];
  __syncthreads();
  for (int t = 64; t > 0; t >>= 1) { if (tid < t) red[tid] += red[tid + t]; __syncthreads(); }
  float mean = red[0] / 384.f;
  __syncthreads();
  float q = 0.f;
#pragma unroll
  for (int i = 0; i < 3; ++i) { float d0 = v[i] - mean; q += d0 * d0; }
  red[tid] = q;
  __syncthreads();
  for (int t = 64; t > 0; t >>= 1) { if (tid < t) red[tid] += red[tid + t]; __syncthreads(); }
  float rstd = rsqrtf(red[0] / 384.f + 1e-5f);
  int bb = row / 96;
#pragma unroll
  for (int i = 0; i < 3; ++i) {
    int d = tid + i * 128;
    float o = (v[i] - mean) * rstd * g[d] + bt[d];
    xout[(long)row * 384 + d] = o;
    xbf[(long)row * 384 + d] = f2bf(o);
    if (modl) {
      float sc = modl[bb * 768 + d];
      float sh = modl[bb * 768 + 384 + d];
      xqb[(long)row * 384 + d] = f2bf(o * (1.f + sc) + sh);
    }
  }
}

// ---------------- tiny final head layer: out[r][ooff..] = A_bf16[r] @ W + b --
__global__ __launch_bounds__(64)
void rowgemm_bf(const unsigned short* __restrict__ A, const float* __restrict__ W,
                const float* __restrict__ bias, float* __restrict__ out,
                int Nc, int ooff) {
  int r = blockIdx.x, tid = threadIdx.x;
  __shared__ float as[384];
  for (int k = tid; k < 384; k += 64) {
    union { unsigned u; float f; } c; c.u = (unsigned)A[(long)r * 384 + k] << 16;
    as[k] = c.f;
  }
  __syncthreads();
  if (tid < Nc) {
    float acc = bias[tid];
    for (int k = 0; k < 384; ++k) acc += as[k] * W[k * Nc + tid];
    out[(long)r * 71 + ooff + tid] = acc;
  }
}

// =============================================================================
extern "C" void kernel_launch(void* const* d_in, const int* in_sizes, int n_in,
                              void* d_out, int out_size, void* d_ws, size_t ws_size,
                              hipStream_t stream) {
  const float* q_in    = (const float*)d_in[0];
  const float* k_cross = (const float*)d_in[1];
  const float* k_self  = (const float*)d_in[2];
  const float* q_xyz   = (const float*)d_in[3];
  const float* k_xyz   = (const float*)d_in[4];
  const float* tsteps  = (const float*)d_in[5];
  const float* t_w1 = (const float*)d_in[6];
  const float* t_b1 = (const float*)d_in[7];
  const float* t_w2 = (const float*)d_in[8];
  const float* t_b2 = (const float*)d_in[9];
  const float* type_emb = (const float*)d_in[10];
  const float* ada_w = (const float*)d_in[11];
  const float* ada_b = (const float*)d_in[12];
  const float* wq = (const float*)d_in[13]; const float* bq = (const float*)d_in[14];
  const float* wk = (const float*)d_in[15]; const float* bk = (const float*)d_in[16];
  const float* wv = (const float*)d_in[17]; const float* bv = (const float*)d_in[18];
  const float* wo = (const float*)d_in[19]; const float* bo = (const float*)d_in[20];
  const float* ln1g = (const float*)d_in[21]; const float* ln1b = (const float*)d_in[22];
  const float* fw1 = (const float*)d_in[23]; const float* fb1 = (const float*)d_in[24];
  const float* fw2 = (const float*)d_in[25]; const float* fb2 = (const float*)d_in[26];
  const float* ln2g = (const float*)d_in[27]; const float* ln2b = (const float*)d_in[28];
  const float* hw[9]; const float* hb[9];
  for (int i = 0; i < 9; ++i) { hw[i] = (const float*)d_in[29 + 2 * i]; hb[i] = (const float*)d_in[30 + 2 * i]; }

  char* ws = (char*)d_ws;
  size_t off = 0;
  auto alloc = [&](size_t bytes) -> void* {
    void* p = ws + off;
    off += (bytes + 255) & ~(size_t)255;
    return p;
  };
  float* s_silu = (float*)alloc((size_t)32 * 384 * 4);
  float* mod    = (float*)alloc((size_t)6 * 32 * 768 * 4);
  __half2* cs_all = (__half2*)alloc((size_t)32 * 2144 * 192 * 4);
  unsigned short* kcb  = (unsigned short*)alloc((size_t)32 * 2048 * 384 * 2);
  unsigned short* ksb  = (unsigned short*)alloc((size_t)32 * 2144 * 384 * 2);
  unsigned short* wqt  = (unsigned short*)alloc((size_t)6 * 384 * 384 * 2);
  unsigned short* wkvt = (unsigned short*)alloc((size_t)6 * 768 * 384 * 2);
  unsigned short* wot  = (unsigned short*)alloc((size_t)6 * 384 * 384 * 2);
  unsigned short* fw1t = (unsigned short*)alloc((size_t)6 * 384 * 1536 * 2);
  unsigned short* fw2t = (unsigned short*)alloc((size_t)6 * 384 * 1536 * 2);
  unsigned short* hwt  = (unsigned short*)alloc((size_t)6 * 384 * 384 * 2);
  float* x            = (float*)alloc((size_t)MQ_ * 384 * 4);
  unsigned short* xbf  = (unsigned short*)alloc((size_t)MQ_ * 384 * 2);
  unsigned short* xqb  = (unsigned short*)alloc((size_t)MQ_ * 384 * 2);
  unsigned short* qrope= (unsigned short*)alloc((size_t)MQ_ * 384 * 2);
  unsigned short* Kc   = (unsigned short*)alloc((size_t)256 * 2144 * 48 * 2);
  unsigned short* Vrm  = (unsigned short*)alloc((size_t)32 * 2144 * 384 * 2);
  unsigned short* aout = (unsigned short*)alloc((size_t)MQ_ * 384 * 2);
  float* tmp          = (float*)alloc((size_t)MQ_ * 384 * 4);
  unsigned short* ffh  = (unsigned short*)alloc((size_t)MQ_ * 1536 * 2);
  unsigned short* hh1  = (unsigned short*)alloc((size_t)1024 * 384 * 2);
  unsigned short* hh2  = (unsigned short*)alloc((size_t)1024 * 384 * 2);
  float* Opart        = (float*)alloc((size_t)SATT * 256 * 96 * 48 * 4);
  float* Lpart        = (float*)alloc((size_t)SATT * 256 * 96 * 4);
  (void)ws_size; (void)in_sizes; (void)n_in; (void)out_size;

  // ---- prep (layer-invariant) ----
  time_embed_kernel<<<32, 384, 0, stream>>>(tsteps, t_w1, t_b1, t_w2, t_b2, s_silu);
  adaln_mod_kernel<<<dim3(32, 6), 768, 0, stream>>>(s_silu, ada_w, ada_b, mod);
  rope_pack_kernel<<<4096, 256, 0, stream>>>(k_xyz, cs_all, 32 * 2048 * 192, 2048, 2144, 0);
  rope_pack_kernel<<<1024, 256, 0, stream>>>(q_xyz, cs_all, 32 * 96 * 192, 96, 2144, 2048);
  cast_type_kernel<<<4096, 256, 0, stream>>>(k_cross, type_emb, kcb, (long)32 * 2048 * 384, 2048);
  cast_type_kernel<<<4096, 256, 0, stream>>>(k_self, type_emb, ksb, (long)32 * 2144 * 384, 2144);
  wtrans_kernel<<<1024, 256, 0, stream>>>(wq, wqt, (long)6 * 384 * 384, 384, 384, 384, 0);
  wtrans_kernel<<<1024, 256, 0, stream>>>(wk, wkvt, (long)6 * 384 * 384, 384, 384, 768, 0);
  wtrans_kernel<<<1024, 256, 0, stream>>>(wv, wkvt, (long)6 * 384 * 384, 384, 384, 768, 384);
  wtrans_kernel<<<1024, 256, 0, stream>>>(wo, wot, (long)6 * 384 * 384, 384, 384, 384, 0);
  wtrans_kernel<<<2048, 256, 0, stream>>>(fw1, fw1t, (long)6 * 384 * 1536, 384, 1536, 1536, 0);
  wtrans_kernel<<<2048, 256, 0, stream>>>(fw2, fw2t, (long)6 * 1536 * 384, 1536, 384, 384, 0);
  for (int hd = 0; hd < 3; ++hd) {   // head weights (layers 1,2) -> bf16 transposed
    wtrans_kernel<<<256, 256, 0, stream>>>(hw[hd * 3 + 0], hwt + (long)(hd * 2) * 384 * 384,
                                           (long)384 * 384, 384, 384, 384, 0);
    wtrans_kernel<<<256, 256, 0, stream>>>(hw[hd * 3 + 1], hwt + (long)(hd * 2 + 1) * 384 * 384,
                                           (long)384 * 384, 384, 384, 384, 0);
  }
  hipMemcpyAsync(x, q_in, (size_t)MQ_ * 384 * 4, hipMemcpyDeviceToDevice, stream);
  modx_kernel<<<(MQ_ * 384 + 255) / 256, 256, 0, stream>>>(x, mod, xqb);

  // ---- 6 transformer layers ----
  for (int l = 0; l < 6; ++l) {
    int Nl = (l < 2) ? 2048 : 2144;
    const unsigned short* kvsrc = (l < 2) ? kcb : ksb;
    gemm_bt<EPI_ROPE_Q, 64, 0, 0><<<dim3(3, 48), 256, 0, stream>>>(
        xqb, wqt + (long)l * 384 * 384, bq + l * 384, nullptr, qrope, nullptr,
        384, 384, cs_all, 2048, 96);
    gemm_bt<EPI_KV, 128, 6, 0><<<dim3(6 * (32 * Nl / 128)), 256, 0, stream>>>(
        kvsrc, wkvt + (long)l * 768 * 384, bk + l * 384, bv + l * 384, Kc, Vrm,
        768, 384, cs_all, 0, Nl);
    attn_part_kernel<<<dim3(8, 32, SATT), 384, 0, stream>>>(qrope, Kc, Vrm, Opart, Lpart, Nl, SATT);
    attn_combine_kernel<<<dim3(8, 32), 384, 0, stream>>>(Opart, Lpart, aout, SATT);
    gemm_bt<EPI_F32, 64, 0, 0><<<dim3(3, 48), 256, 0, stream>>>(
        aout, wot + (long)l * 384 * 384, bo + l * 384, nullptr, tmp, nullptr,
        384, 384, nullptr, 0, 96);
    ln_res_kernel<<<MQ_, 128, 0, stream>>>(x, tmp, ln1g + l * 384, ln1b + l * 384,
                                           nullptr, x, xbf, nullptr);
    gemm_bt<EPI_RELU, 128, 0, 0><<<dim3(12, 24), 256, 0, stream>>>(
        xbf, fw1t + (long)l * 1536 * 384, fb1 + l * 1536, nullptr, ffh, nullptr,
        1536, 384, nullptr, 0, 96);
    gemm_bt<EPI_F32, 64, 0, 0><<<dim3(3, 48), 256, 0, stream>>>(
        ffh, fw2t + (long)l * 384 * 1536, fb2 + l * 384, nullptr, tmp, nullptr,
        384, 1536, nullptr, 0, 96);
    ln_res_kernel<<<MQ_, 128, 0, stream>>>(x, tmp, ln2g + l * 384, ln2b + l * 384,
                                           (l < 5) ? (mod + (long)(l + 1) * 32 * 768) : nullptr,
                                           x, xbf, xqb);
  }

  // ---- MLP heads: 2 MFMA layers (bf16) + tiny fp32 final ----
  const int ooffs[3] = {0, 31, 62};
  const int nouts[3] = {31, 31, 9};
  for (int hd = 0; hd < 3; ++hd) {
    gemm_bt<EPI_RELU, 64, 0, 1><<<dim3(3, 16), 256, 0, stream>>>(
        xbf, hwt + (long)(hd * 2) * 384 * 384, hb[hd * 3 + 0], nullptr, hh1, nullptr,
        384, 384, nullptr, hd * 32, 96);
    gemm_bt<EPI_RELU, 64, 0, 0><<<dim3(3, 16), 256, 0, stream>>>(
        hh1, hwt + (long)(hd * 2 + 1) * 384 * 384, hb[hd * 3 + 1], nullptr, hh2, nullptr,
        384, 384, nullptr, 0, 96);
    rowgemm_bf<<<1024, 64, 0, stream>>>(hh2, hw[hd * 3 + 2], hb[hd * 3 + 2], (float*)d_out,
                                        nouts[hd], ooffs[hd]);
  }
}